// Round 9
// baseline (361.887 us; speedup 1.0000x reference)
//
#include <hip/hip_runtime.h>

// SelfAttention (SAGAN-style), B=4, C=256, N=4096, Dqk=32.
// Round 8 resubmit (broker timeout; never ran): attn = dedup structure,
// KT=256, 512 blocks x 32q, P LDS 16KB -> 4 blocks/CU; NO min-waves bound
// (R7's (512,4) -> VGPR 52 killed ILP). proj: x-load double-buffer.

#define BATCH 4
#define CH    256
#define NPIX  4096
#define DQKD  32

typedef __attribute__((ext_vector_type(8))) short bf16x8;
typedef __attribute__((ext_vector_type(4))) float f32x4;

__device__ __forceinline__ unsigned pk2(float a, float b) {
    return (__float_as_uint(a) >> 16) | (__float_as_uint(b) & 0xffff0000u);
}

// ---------------- projection: q = (Wq x + bq)*log2e, k = Wk x + bk, v = Wv x + bv
__global__ __launch_bounds__(256) void proj_kernel(
    const float* __restrict__ x,
    const float* __restrict__ Wq, const float* __restrict__ bq,
    const float* __restrict__ Wk, const float* __restrict__ bk,
    const float* __restrict__ Wv, const float* __restrict__ bv,
    ushort* __restrict__ qb, ushort* __restrict__ kb, ushort* __restrict__ vb)
{
    __shared__ float w_lds[32][256];
    __shared__ float b_lds[32];
    const int tid = threadIdx.x;
    const int n0  = blockIdx.x * 256;
    const int dt  = blockIdx.y;        // 0:Q, 1:K, 2..9:V rows (dt-2)*32
    const int b   = blockIdx.z;

    const float* W; const float* bias;
    if (dt == 0)      { W = Wq;                              bias = bq; }
    else if (dt == 1) { W = Wk;                              bias = bk; }
    else              { W = Wv + (size_t)(dt - 2) * 32 * CH; bias = bv + (dt - 2) * 32; }

    {
        const float4* w4 = (const float4*)W;
        float4* l4 = (float4*)&w_lds[0][0];
        #pragma unroll
        for (int i = 0; i < 8; ++i) l4[tid + 256 * i] = w4[tid + 256 * i];
        if (tid < 32) b_lds[tid] = bias[tid];
    }
    __syncthreads();

    const int tn = tid & 63;
    const int td = tid >> 6;
    const int n  = n0 + tn * 4;

    float acc[8][4];
    #pragma unroll
    for (int i = 0; i < 8; ++i) {
        float bb = b_lds[td * 8 + i];
        #pragma unroll
        for (int j = 0; j < 4; ++j) acc[i][j] = bb;
    }

    const float* xb = x + (size_t)b * CH * NPIX + n;

    float xa[8][4], xc[8][4];          // double-buffered x chunks (8 c-rows each)
#define LOADX(DST, CBASE)                                              \
    {                                                                  \
        _Pragma("unroll")                                              \
        for (int cc = 0; cc < 8; ++cc) {                               \
            float4 xv = *(const float4*)(xb + (size_t)((CBASE) + cc) * NPIX); \
            DST[cc][0] = xv.x; DST[cc][1] = xv.y;                      \
            DST[cc][2] = xv.z; DST[cc][3] = xv.w;                      \
        }                                                              \
    }
#define FMA8(SRC, CBASE)                                               \
    {                                                                  \
        _Pragma("unroll")                                              \
        for (int i = 0; i < 8; ++i) {                                  \
            _Pragma("unroll")                                          \
            for (int h = 0; h < 2; ++h) {                              \
                float4 w4 = *(const float4*)&w_lds[td * 8 + i][(CBASE) + 4 * h]; \
                float wr[4] = {w4.x, w4.y, w4.z, w4.w};                \
                _Pragma("unroll")                                      \
                for (int cc = 0; cc < 4; ++cc)                         \
                    _Pragma("unroll")                                  \
                    for (int j = 0; j < 4; ++j)                        \
                        acc[i][j] = fmaf(wr[cc], SRC[4 * h + cc][j], acc[i][j]); \
            }                                                          \
        }                                                              \
    }

    LOADX(xa, 0)
    #pragma unroll 1
    for (int c0 = 0; c0 < CH; c0 += 16) {
        LOADX(xc, c0 + 8)
        FMA8(xa, c0)
        if (c0 + 16 < CH) LOADX(xa, c0 + 16)
        FMA8(xc, c0 + 8)
    }
#undef LOADX
#undef FMA8

    if (dt == 0 || dt == 1) {          // Q/K layout [b][n][32] bf16
        ushort* dst = (dt == 0) ? qb : kb;
        const float sc = (dt == 0) ? 1.4426950408889634f : 1.0f;  // Q *= log2(e)
        #pragma unroll
        for (int j = 0; j < 4; ++j) {
            uint4 u;
            u.x = pk2(acc[0][j] * sc, acc[1][j] * sc);
            u.y = pk2(acc[2][j] * sc, acc[3][j] * sc);
            u.z = pk2(acc[4][j] * sc, acc[5][j] * sc);
            u.w = pk2(acc[6][j] * sc, acc[7][j] * sc);
            *(uint4*)(dst + ((size_t)b * NPIX + n + j) * DQKD + td * 8) = u;
        }
    } else {                           // V layout [b][c][n] bf16
        const int cbase = (dt - 2) * 32 + td * 8;
        #pragma unroll
        for (int i = 0; i < 8; ++i) {
            uint2 u;
            u.x = pk2(acc[i][0], acc[i][1]);
            u.y = pk2(acc[i][2], acc[i][3]);
            *(uint2*)(vb + ((size_t)b * CH + cbase + i) * NPIX + n) = u;
        }
    }
}

// ---------------- fused flash attention + residual ---------------------------
// 512 blocks x 512 thr. Block: 32 queries x 256 channels, batch-pinned XCD.
// Outer: 256-key tiles (16 iters). Phase A: wave w -> keys [32w,32w+32) x 32q
// into shared P LDS (16 KB). Phase B: wave (qh, cg) -> 16q x 64ch PV, V dbuf.
// NO min-waves bound: occupancy comes from small LDS (4 blocks/CU).
__global__ __launch_bounds__(512) void attn_kernel(
    const ushort* __restrict__ Qb, const ushort* __restrict__ Kb,
    const ushort* __restrict__ Vb, const float* __restrict__ x,
    const float* __restrict__ gamma_p, float* __restrict__ out)
{
    __shared__ char  p_lds[32 * 512];      // P[32 q][256 k] bf16, pitch 512B
    __shared__ float l_lds[8][32];
    __shared__ float linv_lds[32];

    const int tid  = threadIdx.x;
    const int lane = tid & 63;
    const int wv   = tid >> 6;             // 0..7
    const int l15  = lane & 15, g = lane >> 4;
    const unsigned swz = (unsigned)(l15 & 7) << 4;

    int bid  = blockIdx.x;
    int xcd  = bid & 7, slot = bid >> 3;   // 64 blocks per XCD
    int b    = xcd >> 1;                   // batch pinned to XCD pair
    int qt   = slot + 64 * (xcd & 1);      // 0..127
    const int m0 = qt * 32;

    // Q fragments: 2 x 16-query tiles (B-operand)
    bf16x8 qf[2];
    #pragma unroll
    for (int qc = 0; qc < 2; ++qc)
        qf[qc] = *(const bf16x8*)(Qb + ((size_t)b * NPIX + m0 + 16 * qc + l15) * DQKD + 8 * g);

    const ushort* kbase = Kb + ((size_t)b * NPIX + 32 * wv + l15) * DQKD + 8 * g;

    const int qh = wv >> 2;                // 0..1: rows 16*qh..+15
    const int cg = wv & 3;                 // 0..3: ch 64*cg..+63
    const ushort* vbase = Vb + ((size_t)(b * CH + 64 * cg) + l15) * NPIX + 8 * g;

    f32x4 acc[4];
    #pragma unroll
    for (int ct = 0; ct < 4; ++ct) acc[ct] = (f32x4){0.f, 0.f, 0.f, 0.f};
    float l_run[2] = {0.f, 0.f};

    const f32x4 z4 = {0.f, 0.f, 0.f, 0.f};

    #pragma unroll 1
    for (int kt = 0; kt < NPIX; kt += 256) {
        // ---- Phase A: QK^T + exp2 + P write (own 32-key stripe, 32 q) ----
        {
            bf16x8 kf[2];
            #pragma unroll
            for (int t = 0; t < 2; ++t)
                kf[t] = *(const bf16x8*)(kbase + (size_t)(kt + 16 * t) * DQKD);
            #pragma unroll
            for (int t = 0; t < 2; ++t) {
                #pragma unroll
                for (int qc = 0; qc < 2; ++qc) {
                    f32x4 st = __builtin_amdgcn_mfma_f32_16x16x32_bf16(kf[t], qf[qc], z4, 0, 0, 0);
                    float p0 = exp2f(st[0]);
                    float p1 = exp2f(st[1]);
                    float p2 = exp2f(st[2]);
                    float p3 = exp2f(st[3]);
                    l_run[qc] += (p0 + p1) + (p2 + p3);
                    unsigned row = 16 * qc + l15;
                    unsigned off = row * 512 + ((64u * wv + 32u * t + 8u * g) ^ swz);
                    uint2 u; u.x = pk2(p0, p1); u.y = pk2(p2, p3);
                    *(uint2*)(p_lds + off) = u;
                }
            }
        }
        __syncthreads();

        // ---- Phase B: PV over 256 keys, 16q x 64ch per wave, V dbuf ----
        {
            bf16x8 va[4], vn[4];
            #pragma unroll
            for (int ct = 0; ct < 4; ++ct)
                va[ct] = *(const bf16x8*)(vbase + (size_t)(16 * ct) * NPIX + kt);

#define PV_STEP(CUR, NXT, KS)                                                   \
            {                                                                   \
                if ((KS) < 7) {                                                 \
                    _Pragma("unroll")                                           \
                    for (int ct = 0; ct < 4; ++ct)                              \
                        NXT[ct] = *(const bf16x8*)(vbase + (size_t)(16 * ct) * NPIX \
                                                   + kt + 32 * ((KS) + 1));     \
                }                                                               \
                unsigned off = (16u * qh + l15) * 512u + ((64u * (KS) + 16u * g) ^ swz); \
                bf16x8 pa = *(const bf16x8*)(p_lds + off);                      \
                _Pragma("unroll")                                               \
                for (int ct = 0; ct < 4; ++ct)                                  \
                    acc[ct] = __builtin_amdgcn_mfma_f32_16x16x32_bf16(          \
                        pa, CUR[ct], acc[ct], 0, 0, 0);                         \
            }

            #pragma unroll
            for (int ks2 = 0; ks2 < 4; ++ks2) {
                PV_STEP(va, vn, 2 * ks2);
                PV_STEP(vn, va, 2 * ks2 + 1);
            }
#undef PV_STEP
        }
        __syncthreads();
    }

    // ---- l reduction: per-wave partials -> block totals ----
    #pragma unroll
    for (int qc = 0; qc < 2; ++qc) {
        l_run[qc] += __shfl_xor(l_run[qc], 16);
        l_run[qc] += __shfl_xor(l_run[qc], 32);
        if (g == 0) l_lds[wv][16 * qc + l15] = l_run[qc];
    }
    __syncthreads();
    if (tid < 32) {
        float s = 0.f;
        #pragma unroll
        for (int w = 0; w < 8; ++w) s += l_lds[w][tid];
        linv_lds[tid] = 1.0f / s;
    }
    __syncthreads();

    // ---- epilogue: out = gamma*(acc/l) + x ----
    const float gm = gamma_p[0];
    float4 li = *(const float4*)&linv_lds[16 * qh + 4 * g];
    #pragma unroll
    for (int ct = 0; ct < 4; ++ct) {
        size_t o = ((size_t)b * CH + 64 * cg + 16 * ct + l15) * NPIX
                 + m0 + 16 * qh + 4 * g;
        float4 xv = *(const float4*)(x + o);
        float4 ov;
        ov.x = fmaf(gm, acc[ct][0] * li.x, xv.x);
        ov.y = fmaf(gm, acc[ct][1] * li.y, xv.y);
        ov.z = fmaf(gm, acc[ct][2] * li.z, xv.z);
        ov.w = fmaf(gm, acc[ct][3] * li.w, xv.w);
        *(float4*)(out + o) = ov;
    }
}

extern "C" void kernel_launch(void* const* d_in, const int* in_sizes, int n_in,
                              void* d_out, int out_size, void* d_ws, size_t ws_size,
                              hipStream_t stream)
{
    (void)in_sizes; (void)n_in; (void)out_size; (void)ws_size;
    const float* x  = (const float*)d_in[0];
    const float* Wq = (const float*)d_in[1];
    const float* bq = (const float*)d_in[2];
    const float* Wk = (const float*)d_in[3];
    const float* bk = (const float*)d_in[4];
    const float* Wv = (const float*)d_in[5];
    const float* bv = (const float*)d_in[6];
    const float* gm = (const float*)d_in[7];
    float* out = (float*)d_out;

    ushort* qw = (ushort*)d_ws;
    ushort* kw = qw + (size_t)BATCH * NPIX * DQKD;
    ushort* vw = kw + (size_t)BATCH * NPIX * DQKD;

    dim3 g1(NPIX / 256, 10, BATCH);
    proj_kernel<<<g1, 256, 0, stream>>>(x, Wq, bq, Wk, bk, Wv, bv, qw, kw, vw);

    attn_kernel<<<dim3(512), 512, 0, stream>>>(qw, kw, vw, x, gm, out);
}

// Round 10
// 219.724 us; speedup vs baseline: 1.6470x; 1.6470x over previous
//
#include <hip/hip_runtime.h>

// SelfAttention (SAGAN-style), B=4, C=256, N=4096, Dqk=32.
// Round 10: async global_load_lds staging for BOTH kernels (compiler sinks
// register prefetches -> VGPR 52 serial chains in R7/R9; DMA can't be sunk).
// attn: 256 blocks x 64q x 256ch, KT=64, K/V dbuf LDS + P LDS, 2-phase raw
// barriers (lgkmcnt / vmcnt). Swizzled LDS via pre-swizzled global source.

#define BATCH 4
#define CH    256
#define NPIX  4096
#define DQKD  32
#define KT    64
#define NT    (NPIX / KT)

typedef __attribute__((ext_vector_type(8))) short bf16x8;
typedef __attribute__((ext_vector_type(4))) float f32x4;

__device__ __forceinline__ unsigned pk2(float a, float b) {
    return (__float_as_uint(a) >> 16) | (__float_as_uint(b) & 0xffff0000u);
}

__device__ __forceinline__ void gl16(const void* g, void* l) {
    __builtin_amdgcn_global_load_lds(
        (const __attribute__((address_space(1))) void*)g,
        (__attribute__((address_space(3))) void*)l, 16, 0, 0);
}

// ---------------- projection: q = (Wq x + bq)*log2e, k = Wk x + bk, v = Wv x + bv
__global__ __launch_bounds__(256) void proj_kernel(
    const float* __restrict__ x,
    const float* __restrict__ Wq, const float* __restrict__ bq,
    const float* __restrict__ Wk, const float* __restrict__ bk,
    const float* __restrict__ Wv, const float* __restrict__ bv,
    ushort* __restrict__ qb, ushort* __restrict__ kb, ushort* __restrict__ vb)
{
    __shared__ float w_lds[32][256];       // 32 KB
    __shared__ float b_lds[32];
    __shared__ float x_lds[2][8][256];     // 16 KB dbuf, DMA-staged

    const int tid = threadIdx.x;
    const int n0  = blockIdx.x * 256;
    const int dt  = blockIdx.y;            // 0:Q, 1:K, 2..9:V rows (dt-2)*32
    const int b   = blockIdx.z;

    const float* W; const float* bias;
    if (dt == 0)      { W = Wq;                              bias = bq; }
    else if (dt == 1) { W = Wk;                              bias = bk; }
    else              { W = Wv + (size_t)(dt - 2) * 32 * CH; bias = bv + (dt - 2) * 32; }

    const float* psrc = x + (size_t)b * CH * NPIX + n0 + 4 * (tid & 63);

#define PSTAGE(C0, BUF) {                                                     \
        _Pragma("unroll")                                                     \
        for (int j = 0; j < 2; ++j) {                                         \
            int chunk = 2 * (tid >> 6) + j;                                   \
            gl16(psrc + (size_t)((C0) + chunk) * NPIX, &x_lds[BUF][chunk][0]);\
        } }

    PSTAGE(0, 0)
    {
        const float4* w4 = (const float4*)W;
        float4* l4 = (float4*)&w_lds[0][0];
        #pragma unroll
        for (int i = 0; i < 8; ++i) l4[tid + 256 * i] = w4[tid + 256 * i];
        if (tid < 32) b_lds[tid] = bias[tid];
    }
    __syncthreads();                       // drains vmcnt (DMA) + lgkm

    const int tn = tid & 63;
    const int td = tid >> 6;
    const int n  = n0 + tn * 4;

    float acc[8][4];
    #pragma unroll
    for (int i = 0; i < 8; ++i) {
        float bb = b_lds[td * 8 + i];
        #pragma unroll
        for (int j = 0; j < 4; ++j) acc[i][j] = bb;
    }

    int cur = 0;
    #pragma unroll 1
    for (int t = 0; t < 32; ++t) {
        if (t + 1 < 32) PSTAGE(8 * t + 8, cur ^ 1)
        #pragma unroll
        for (int h = 0; h < 2; ++h) {
            float xr[4][4];
            #pragma unroll
            for (int cc = 0; cc < 4; ++cc) {
                float4 xv = *(const float4*)&x_lds[cur][4 * h + cc][4 * tn];
                xr[cc][0] = xv.x; xr[cc][1] = xv.y; xr[cc][2] = xv.z; xr[cc][3] = xv.w;
            }
            #pragma unroll
            for (int i = 0; i < 8; ++i) {
                float4 w4 = *(const float4*)&w_lds[td * 8 + i][8 * t + 4 * h];
                float wr[4] = {w4.x, w4.y, w4.z, w4.w};
                #pragma unroll
                for (int cc = 0; cc < 4; ++cc)
                    #pragma unroll
                    for (int j = 0; j < 4; ++j)
                        acc[i][j] = fmaf(wr[cc], xr[cc][j], acc[i][j]);
            }
        }
        __syncthreads();                   // DMA drain + buffer-reuse order
        cur ^= 1;
    }
#undef PSTAGE

    if (dt == 0 || dt == 1) {              // Q/K layout [b][n][32] bf16
        ushort* dst = (dt == 0) ? qb : kb;
        const float sc = (dt == 0) ? 1.4426950408889634f : 1.0f;  // Q *= log2(e)
        #pragma unroll
        for (int j = 0; j < 4; ++j) {
            uint4 u;
            u.x = pk2(acc[0][j] * sc, acc[1][j] * sc);
            u.y = pk2(acc[2][j] * sc, acc[3][j] * sc);
            u.z = pk2(acc[4][j] * sc, acc[5][j] * sc);
            u.w = pk2(acc[6][j] * sc, acc[7][j] * sc);
            *(uint4*)(dst + ((size_t)b * NPIX + n + j) * DQKD + td * 8) = u;
        }
    } else {                               // V layout [b][c][n] bf16
        const int cbase = (dt - 2) * 32 + td * 8;
        #pragma unroll
        for (int i = 0; i < 8; ++i) {
            uint2 u;
            u.x = pk2(acc[i][0], acc[i][1]);
            u.y = pk2(acc[i][2], acc[i][3]);
            *(uint2*)(vb + ((size_t)b * CH + cbase + i) * NPIX + n) = u;
        }
    }
}

// ---------------- fused flash attention + residual ---------------------------
// 256 blocks x 512 thr (1 block/CU). Block: 64q x 256ch, batch-pinned XCD.
// Per 64-key tile: STAGE(next K 4KB + V 32KB via global_load_lds, dbuf) ->
// phase A (QK^T + exp2 -> P LDS) -> lgkmcnt+barrier -> phase B (PV from LDS)
// -> vmcnt+barrier. LDS swizzle: linear dest + pre-swizzled global source,
// matching XOR on reads (rule #21).
__global__ __launch_bounds__(512) void attn_kernel(
    const ushort* __restrict__ Qb, const ushort* __restrict__ Kb,
    const ushort* __restrict__ Vb, const float* __restrict__ x,
    const float* __restrict__ gamma_p, float* __restrict__ out)
{
    __shared__ char v_lds[2][32 * 1024];   // V tile [256 ch][64 k] bf16, swz
    __shared__ char k_lds[2][4 * 1024];    // K tile [64 k][32 d] bf16, swz
    __shared__ char p_lds[64 * 128];       // P [64 q][64 k] bf16, swz
    __shared__ float l_lds[2][64];
    __shared__ float linv_lds[64];

    const int tid  = threadIdx.x;
    const int lane = tid & 63;
    const int wv   = tid >> 6;             // 0..7
    const int l15  = lane & 15, g = lane >> 4;

    int bid  = blockIdx.x;
    int xcd  = bid & 7, slot = bid >> 3;   // 32 blocks/XCD
    int b    = xcd >> 1;                   // batch pinned to XCD pair
    int unit = slot + 32 * (xcd & 1);      // 0..63
    const int m0 = unit * 64;

    const int qc_a = wv & 3, kt2 = wv >> 2;   // phase A: q-tile, key-half
    const int qh   = wv >> 2, cg = wv & 3;    // phase B: q-half, ch-group

    // Q fragment (B-operand), held whole kernel
    const bf16x8 qf = *(const bf16x8*)(Qb + ((size_t)b * NPIX + m0 + 16 * qc_a + l15) * DQKD + 8 * g);

    // staging sources (pre-swizzled per-lane global addresses)
    const int vxo = ((lane & 7) ^ ((lane >> 3) & 7)) * 8;   // key elems within tile
    const ushort* vsrc0 = Vb + ((size_t)b * CH + 32 * wv + (lane >> 3)) * NPIX + vxo;
    const int kxo = ((lane & 3) ^ ((lane >> 2) & 3)) * 8;   // d elems within row
    const ushort* ksrc0 = Kb + ((size_t)b * NPIX + 16 * wv + (lane >> 2)) * DQKD + kxo;

    f32x4 acc[2][4];
    #pragma unroll
    for (int q2 = 0; q2 < 2; ++q2)
        #pragma unroll
        for (int ct = 0; ct < 4; ++ct) acc[q2][ct] = (f32x4){0.f, 0.f, 0.f, 0.f};
    float l_run = 0.f;
    const f32x4 z4 = {0.f, 0.f, 0.f, 0.f};

#define STAGE(KTILE, BUF) {                                                       \
        _Pragma("unroll")                                                         \
        for (int j = 0; j < 4; ++j)                                               \
            gl16(vsrc0 + (size_t)j * 8 * NPIX + (KTILE),                          \
                 &v_lds[BUF][wv * 4096 + j * 1024]);                              \
        if (wv < 4)                                                               \
            gl16(ksrc0 + (size_t)(KTILE) * DQKD, &k_lds[BUF][wv * 1024]);         \
    }

    STAGE(0, 0)
    asm volatile("s_waitcnt vmcnt(0)" ::: "memory");
    __builtin_amdgcn_s_barrier();

    const int kswz = (g ^ (l15 & 3)) * 16;     // K-read XOR (const per thread)
    int cur = 0;
    #pragma unroll 1
    for (int t = 0; t < NT; ++t) {
        if (t + 1 < NT) STAGE((t + 1) * KT, cur ^ 1)

        // ---- phase A: QK^T + exp2 -> P LDS (wave: q-tile qc_a, keys kt2-half)
        {
            const char* kbuf = &k_lds[cur][0];
            int kr0 = 16 * (2 * kt2 + 0) + l15;
            int kr1 = 16 * (2 * kt2 + 1) + l15;
            bf16x8 kf0 = *(const bf16x8*)(kbuf + kr0 * 64 + kswz);
            bf16x8 kf1 = *(const bf16x8*)(kbuf + kr1 * 64 + kswz);
            f32x4 st0 = __builtin_amdgcn_mfma_f32_16x16x32_bf16(kf0, qf, z4, 0, 0, 0);
            f32x4 st1 = __builtin_amdgcn_mfma_f32_16x16x32_bf16(kf1, qf, z4, 0, 0, 0);

            const int prow = 16 * qc_a + l15;
            const int rx = prow & 7;
            {
                float p0 = exp2f(st0[0]), p1 = exp2f(st0[1]);
                float p2 = exp2f(st0[2]), p3 = exp2f(st0[3]);
                l_run += (p0 + p1) + (p2 + p3);
                unsigned off = prow * 128 + (((2 * (2 * kt2 + 0) + (g >> 1)) ^ rx) * 16) + (g & 1) * 8;
                uint2 u; u.x = pk2(p0, p1); u.y = pk2(p2, p3);
                *(uint2*)&p_lds[off] = u;
            }
            {
                float p0 = exp2f(st1[0]), p1 = exp2f(st1[1]);
                float p2 = exp2f(st1[2]), p3 = exp2f(st1[3]);
                l_run += (p0 + p1) + (p2 + p3);
                unsigned off = prow * 128 + (((2 * (2 * kt2 + 1) + (g >> 1)) ^ rx) * 16) + (g & 1) * 8;
                uint2 u; u.x = pk2(p0, p1); u.y = pk2(p2, p3);
                *(uint2*)&p_lds[off] = u;
            }
        }
        asm volatile("s_waitcnt lgkmcnt(0)" ::: "memory");
        __builtin_amdgcn_sched_barrier(0);
        __builtin_amdgcn_s_barrier();

        // ---- phase B: PV (wave: 32q half x 64ch group), operands from LDS
        {
            const char* vbuf = &v_lds[cur][0];
            #pragma unroll
            for (int ks = 0; ks < 2; ++ks) {
                const int gx = ((4 * ks + g) ^ (l15 & 7)) * 16;
                int r0 = 32 * qh + l15;
                bf16x8 pa0 = *(const bf16x8*)&p_lds[r0 * 128 + gx];
                bf16x8 pa1 = *(const bf16x8*)&p_lds[(r0 + 16) * 128 + gx];
                #pragma unroll
                for (int ct = 0; ct < 4; ++ct) {
                    int vrow = 64 * cg + 16 * ct + l15;
                    bf16x8 vf = *(const bf16x8*)(vbuf + vrow * 128 + gx);
                    acc[0][ct] = __builtin_amdgcn_mfma_f32_16x16x32_bf16(pa0, vf, acc[0][ct], 0, 0, 0);
                    acc[1][ct] = __builtin_amdgcn_mfma_f32_16x16x32_bf16(pa1, vf, acc[1][ct], 0, 0, 0);
                }
            }
        }
        asm volatile("s_waitcnt vmcnt(0)" ::: "memory");
        __builtin_amdgcn_sched_barrier(0);
        __builtin_amdgcn_s_barrier();
        cur ^= 1;
    }
#undef STAGE

    // ---- l reduction ----
    l_run += __shfl_xor(l_run, 16);
    l_run += __shfl_xor(l_run, 32);
    if (lane < 16) l_lds[kt2][16 * qc_a + l15] = l_run;
    __syncthreads();
    if (tid < 64) linv_lds[tid] = 1.0f / (l_lds[0][tid] + l_lds[1][tid]);
    __syncthreads();

    // ---- epilogue: out = gamma*(acc/l) + x ----
    const float gm = gamma_p[0];
    #pragma unroll
    for (int qc2 = 0; qc2 < 2; ++qc2) {
        float4 li = *(const float4*)&linv_lds[32 * qh + 16 * qc2 + 4 * g];
        #pragma unroll
        for (int ct = 0; ct < 4; ++ct) {
            size_t o = ((size_t)b * CH + 64 * cg + 16 * ct + l15) * NPIX
                     + m0 + 32 * qh + 16 * qc2 + 4 * g;
            float4 xv = *(const float4*)(x + o);
            float4 ov;
            ov.x = fmaf(gm, acc[qc2][ct][0] * li.x, xv.x);
            ov.y = fmaf(gm, acc[qc2][ct][1] * li.y, xv.y);
            ov.z = fmaf(gm, acc[qc2][ct][2] * li.z, xv.z);
            ov.w = fmaf(gm, acc[qc2][ct][3] * li.w, xv.w);
            *(float4*)(out + o) = ov;
        }
    }
}

extern "C" void kernel_launch(void* const* d_in, const int* in_sizes, int n_in,
                              void* d_out, int out_size, void* d_ws, size_t ws_size,
                              hipStream_t stream)
{
    (void)in_sizes; (void)n_in; (void)out_size; (void)ws_size;
    const float* x  = (const float*)d_in[0];
    const float* Wq = (const float*)d_in[1];
    const float* bq = (const float*)d_in[2];
    const float* Wk = (const float*)d_in[3];
    const float* bk = (const float*)d_in[4];
    const float* Wv = (const float*)d_in[5];
    const float* bv = (const float*)d_in[6];
    const float* gm = (const float*)d_in[7];
    float* out = (float*)d_out;

    ushort* qw = (ushort*)d_ws;
    ushort* kw = qw + (size_t)BATCH * NPIX * DQKD;
    ushort* vw = kw + (size_t)BATCH * NPIX * DQKD;

    dim3 g1(NPIX / 256, 10, BATCH);
    proj_kernel<<<g1, 256, 0, stream>>>(x, Wq, bq, Wk, bk, Wv, bv, qw, kw, vw);

    attn_kernel<<<dim3(256), 512, 0, stream>>>(qw, kw, vw, x, gm, out);
}